// Round 6
// baseline (72.571 us; speedup 1.0000x reference)
//
#include <hip/hip_runtime.h>

// VectorQuantizer on MI355X (gfx950) — v6 "single fused kernel".
// out[0 .. 8388607] = codebook[argmin_k ||z - E_k||^2]   (f32)
// out[8388608]      = 1.25 * mean((z_q - z)^2)           (f32)
//
// Score: maximize  s + ca,  s = z.(1024 E_k) via bf16 MFMA, ca = 128 -
// ||1024 E_k||^2/2048 as the MFMA C-operand.  Key = (bits(s+ca) & 0xFFFFFC00)
// | (1023-col); u32 max = argmax + earliest-col tie-break (np.argmin rule).
// Loss fused: ||q-z||^2_row = ||z||^2 + (128 - v*)/512.
//
// v6: ONE kernel, 256 blocks x 512 threads, 1 block/CU (132 KB dynamic LDS).
// Per block: convert raw f32 codebook -> bf16 LDS (reg-staged ds_write_b128,
// swizzled directly; slot c^(code&7) spans all 32 banks), compute ca in-reg.
// Each wave owns 64 rows and does ONE sweep of all 1024 codes (m=4: B reads
// amortized over 64 rows -> ~half the LDS traffic of v5).  Loss finalized by
// the last block (device-scope atomic counter + acquire/release part[] I/O).

typedef __attribute__((ext_vector_type(8))) short bf16x8;
typedef __attribute__((ext_vector_type(4))) float f32x4;

#define N_TOKENS 131072
#define DIM 64
#define DYN_LDS 135168   // 128 KB bf16 codebook + 4 KB ca

__device__ __forceinline__ short f32_bf16(float f) {
  unsigned u = __builtin_bit_cast(unsigned, f);
  unsigned r = u + 0x7FFFu + ((u >> 16) & 1u);   // round-to-nearest-even
  return (short)(r >> 16);
}

__global__ __launch_bounds__(512, 2) void vq_fused(
    const float* __restrict__ z, const float* __restrict__ cb,
    float* __restrict__ out, double* __restrict__ part,
    unsigned* __restrict__ cnt) {
  extern __shared__ char lds[];
  unsigned short* Bs = (unsigned short*)lds;     // [1024 codes][64 dims] bf16, swizzled
  float* ca_s = (float*)(lds + 131072);          // [1024]
  __shared__ float sml[8];
  __shared__ int lastflag;
  __shared__ double swav[8];

  const int tid = threadIdx.x, lane = tid & 63, wv = tid >> 6;
  const int g = lane >> 4, c15 = lane & 15, sw = c15 & 7;
  const size_t wrow = (size_t)blockIdx.x * 512 + (size_t)wv * 64;
  const unsigned kmask = 0xFFFFFC00u;

  // ---- issue A (z) loads first: 64 rows x 64 dims f32, 16 x f32x4 per lane
  f32x4 a[4][2][2];
  const float* zb = z + wrow * DIM;
  #pragma unroll
  for (int m = 0; m < 4; ++m)
    #pragma unroll
    for (int kk = 0; kk < 2; ++kk) {
      const float* p = zb + (m * 16 + c15) * DIM + kk * 32 + g * 8;
      a[m][kk][0] = *(const f32x4*)p;
      a[m][kk][1] = *(const f32x4*)(p + 4);
    }

  // ---- stage codebook: thread owns codes tid and tid+512; f32 -> bf16*1024,
  //      ds_write_b128 directly to swizzled slot c^(code&7); ca per-thread.
  #pragma unroll
  for (int cc = 0; cc < 2; ++cc) {
    const int code = tid + cc * 512;
    const f32x4* src = (const f32x4*)(cb + code * DIM);
    float sq = 0.0f;
    #pragma unroll
    for (int c = 0; c < 8; ++c) {
      const f32x4 u = src[c * 2], v = src[c * 2 + 1];
      bf16x8 w;
      #pragma unroll
      for (int j = 0; j < 4; ++j) {
        const float e0 = u[j] * 1024.0f;   // exact pow2 scale
        const float e1 = v[j] * 1024.0f;
        w[j]     = f32_bf16(e0);
        w[j + 4] = f32_bf16(e1);
        sq += e0 * e0 + e1 * e1;
      }
      *(bf16x8*)((char*)Bs + code * 128 + ((c ^ (code & 7)) << 4)) = w;
    }
    ca_s[code] = 128.0f - sq * (1.0f / 2048.0f);
  }
  __syncthreads();   // codebook + ca resident (the kernel's only staging barrier)

  // ---- convert A to bf16 fragments + exact-f32 zsq
  bf16x8 ah[4][2];
  float zsq = 0.0f;
  #pragma unroll
  for (int m = 0; m < 4; ++m)
    #pragma unroll
    for (int kk = 0; kk < 2; ++kk)
      #pragma unroll
      for (int j = 0; j < 4; ++j) {
        const float v0 = a[m][kk][0][j], v1 = a[m][kk][1][j];
        ah[m][kk][j]     = f32_bf16(v0);
        ah[m][kk][j + 4] = f32_bf16(v1);
        zsq += v0 * v0 + v1 * v1;
      }

  // ---- single sweep: 64 rows x all 1024 codes, zero barriers
  unsigned best[4][4];
  #pragma unroll
  for (int m = 0; m < 4; ++m)
    #pragma unroll
    for (int r = 0; r < 4; ++r) best[m][r] = 0u;

  const char* bsp = (const char*)Bs;
  const int bx0 = (g ^ sw) << 4;         // kk=0 chunk slot (swizzled)
  const int bx1 = ((4 + g) ^ sw) << 4;   // kk=1 chunk slot

  #pragma unroll 2
  for (int t = 0; t < 32; ++t) {
    bf16x8 bf[2][2];
    #pragma unroll
    for (int n = 0; n < 2; ++n) {
      const int rowb = (t * 32 + n * 16 + c15) * 128;
      bf[n][0] = *(const bf16x8*)(bsp + rowb + bx0);
      bf[n][1] = *(const bf16x8*)(bsp + rowb + bx1);
    }
    #pragma unroll
    for (int n = 0; n < 2; ++n) {
      const float can = ca_s[t * 32 + n * 16 + c15];
      const f32x4 cv = {can, can, can, can};
      const unsigned cc = 1023u - (unsigned)(t * 32 + n * 16 + c15);
      #pragma unroll
      for (int m = 0; m < 4; ++m) {
        f32x4 acc = __builtin_amdgcn_mfma_f32_16x16x32_bf16(
            ah[m][0], bf[n][0], cv, 0, 0, 0);
        acc = __builtin_amdgcn_mfma_f32_16x16x32_bf16(
            ah[m][1], bf[n][1], acc, 0, 0, 0);
        #pragma unroll
        for (int r = 0; r < 4; ++r) {
          const unsigned key =
              (__builtin_bit_cast(unsigned, acc[r]) & kmask) | cc;  // v_and_or
          best[m][r] = key > best[m][r] ? key : best[m][r];         // v_max_u32
        }
      }
    }
  }

  // ---- epilogue: in-wave winner resolve, gather cb row -> out, loss partial
  float lossx = 0.0f;
  const f32x4* cb4 = (const f32x4*)cb;
  f32x4* out4 = (f32x4*)out;
  #pragma unroll
  for (int m = 0; m < 4; ++m)
    #pragma unroll
    for (int r = 0; r < 4; ++r) {
      unsigned bk = best[m][r];
      #pragma unroll
      for (int w = 1; w < 16; w <<= 1) {
        const unsigned ob = (unsigned)__shfl_xor((int)bk, w, 64);
        bk = ob > bk ? ob : bk;
      }
      const int row = m * 16 + g * 4 + r;          // within wave's 64
      const int bi = 1023 - (int)(bk & 1023u);
      out4[(wrow + row) * 16 + c15] = cb4[bi * 16 + c15];
      if (c15 == 0) lossx += 128.0f - __builtin_bit_cast(float, bk & kmask);
    }

  // ---- per-block loss partial (deterministic)
  float psum = zsq + lossx * (1.0f / 512.0f);
  #pragma unroll
  for (int w = 32; w >= 1; w >>= 1) psum += __shfl_xor(psum, w, 64);
  if (lane == 0) sml[wv] = psum;
  __syncthreads();
  if (tid == 0) {
    double t = 0.0;
    #pragma unroll
    for (int i = 0; i < 8; ++i) t += (double)sml[i];
    __hip_atomic_store(&part[blockIdx.x], t, __ATOMIC_RELEASE,
                       __HIP_MEMORY_SCOPE_AGENT);
    const unsigned old = __hip_atomic_fetch_add(cnt, 1u, __ATOMIC_ACQ_REL,
                                                __HIP_MEMORY_SCOPE_AGENT);
    lastflag = (old == 255u);
  }
  __syncthreads();

  // ---- last block finalizes the loss scalar (deterministic reduce order)
  if (lastflag) {
    double v = 0.0;
    if (tid < 256)
      v = __hip_atomic_load(&part[tid], __ATOMIC_ACQUIRE,
                            __HIP_MEMORY_SCOPE_AGENT);
    #pragma unroll
    for (int w = 32; w >= 1; w >>= 1) v += __shfl_xor(v, w, 64);
    if (lane == 0) swav[wv] = v;
    __syncthreads();
    if (tid == 0) {
      double s = 0.0;
      #pragma unroll
      for (int i = 0; i < 8; ++i) s += swav[i];
      out[(size_t)N_TOKENS * DIM] =
          (float)(1.25 * s / ((double)N_TOKENS * (double)DIM));
    }
  }
}

extern "C" void kernel_launch(void* const* d_in, const int* in_sizes, int n_in,
                              void* d_out, int out_size, void* d_ws, size_t ws_size,
                              hipStream_t stream) {
  const float* z = (const float*)d_in[0];
  const float* cb = (const float*)d_in[1];
  float* out = (float*)d_out;
  char* ws = (char*)d_ws;

  // workspace layout (2056 bytes used)
  unsigned* cnt = (unsigned*)(ws);                 // 4 B  arrival counter
  double* part = (double*)(ws + 8);                // 2 KB per-block loss partials

  (void)hipFuncSetAttribute((const void*)vq_fused,
                            hipFuncAttributeMaxDynamicSharedMemorySize, DYN_LDS);

  hipMemsetAsync(cnt, 0, sizeof(unsigned), stream);   // capture-legal stream op
  vq_fused<<<256, 512, DYN_LDS, stream>>>(z, cb, out, part, cnt);
}

// Round 7
// 34.960 us; speedup vs baseline: 2.0758x; 2.0758x over previous
//
#include <hip/hip_runtime.h>

// VectorQuantizer on MI355X (gfx950) — v7 = v5 skeleton + m=4 single sweep.
// out[0 .. 8388607] = codebook[argmin_k ||z - E_k||^2]   (f32)
// out[8388608]      = 1.25 * mean((z_q - z)^2)           (f32)
//
// Score: maximize  s + ca,  s = z.(1024 E_k) via bf16 MFMA, ca = 128 -
// ||1024 E_k||^2/2048 as the MFMA C-operand.  Key = (bits(s+ca) & 0xFFFFFC00)
// | (1023-col); u32 max = argmax + earliest-col tie-break (np.argmin rule).
// Loss fused: ||q-z||^2_row = ||z||^2 + (128 - v*)/512.
//
// v7: 256 blocks x 512 threads, 1 block/CU, 132 KB dynamic LDS.  Whole bf16
// codebook DMA-staged once via global_load_lds (source-XOR-swizzled, linear
// dest — zero VGPR cost, the v5 property v6 lost).  Each wave owns 64 rows
// and sweeps all 1024 codes ONCE (half the LDS B-traffic of v5's two m=2
// passes), with explicitly named ping-pong B registers so tile t+1's ds_reads
// overlap tile t's MFMAs.  A loaded in two 32-row halves to cap f32 register
// footprint at 32 VGPRs (v6's 64-reg blob triggered the 80-VGPR squeeze).

typedef __attribute__((ext_vector_type(8))) short bf16x8;
typedef __attribute__((ext_vector_type(4))) float f32x4;

#define N_TOKENS 131072
#define DIM 64
#define DYN_LDS 135168   // 128 KB bf16 codebook + 4 KB ca

__device__ __forceinline__ short f32_bf16(float f) {
  unsigned u = __builtin_bit_cast(unsigned, f);
  unsigned r = u + 0x7FFFu + ((u >> 16) & 1u);   // round-to-nearest-even
  return (short)(r >> 16);
}

// ---------------- kernel 1: codebook prep -------------------------------------
__global__ __launch_bounds__(256) void vq_prep(
    const float* __restrict__ cb, unsigned short* __restrict__ ch,
    float* __restrict__ ca2) {
  const int lane = threadIdx.x & 63;
  const int wv = threadIdx.x >> 6;
  const int code = blockIdx.x * 4 + wv;      // 256 blocks * 4 waves = 1024 codes
  const float e = cb[code * DIM + lane] * 1024.0f;   // exact pow2 scale
  ch[code * DIM + lane] = (unsigned short)f32_bf16(e);
  float sq = e * e;
  #pragma unroll
  for (int w = 32; w >= 1; w >>= 1) sq += __shfl_xor(sq, w, 64);
  if (lane == 0) ca2[code] = 128.0f - sq * (1.0f / 2048.0f);
}

// ---------------- kernel 2: persistent-codebook argmin + gather + loss --------
__global__ __launch_bounds__(512, 2) void vq_argmin(
    const float* __restrict__ z, const unsigned short* __restrict__ ch,
    const float* __restrict__ ca2, const float* __restrict__ cb,
    float* __restrict__ out, double* __restrict__ part) {
  extern __shared__ char lds[];
  unsigned short* Bs = (unsigned short*)lds;     // [1024 codes][64 dims] bf16, swizzled
  float* ca_s = (float*)(lds + 131072);          // [1024]
  __shared__ float sml[8];

  const int tid = threadIdx.x, lane = tid & 63, wv = tid >> 6;
  const int g = lane >> 4, c15 = lane & 15, sw = c15 & 7;
  const size_t wrow = (size_t)blockIdx.x * 512 + (size_t)wv * 64;
  const unsigned kmask = 0xFFFFFC00u;

  // ---- DMA-stage codebook (+ca) into LDS; source XOR-swizzled, dest linear
  #pragma unroll
  for (int q = 0; q < 16; ++q) {
    const int chunk = q * 512 + tid;           // 16B chunk id, 0..8191
    const int code = chunk >> 3, c = chunk & 7;
    __builtin_amdgcn_global_load_lds(
        (const __attribute__((address_space(1))) unsigned int*)
            (ch + code * DIM + ((c ^ (code & 7)) << 3)),
        (__attribute__((address_space(3))) unsigned int*)(Bs + chunk * 8),
        16, 0, 0);
  }
  if (tid < 256)
    __builtin_amdgcn_global_load_lds(
        (const __attribute__((address_space(1))) unsigned int*)(ca2 + tid * 4),
        (__attribute__((address_space(3))) unsigned int*)(ca_s + tid * 4),
        16, 0, 0);

  // ---- half-0 A loads (rows 0..31 of the wave), in flight across the barrier
  f32x4 a0[2][2][2];
  const float* zb = z + wrow * DIM;
  #pragma unroll
  for (int m = 0; m < 2; ++m)
    #pragma unroll
    for (int kk = 0; kk < 2; ++kk) {
      const float* p = zb + (m * 16 + c15) * DIM + kk * 32 + g * 8;
      a0[m][kk][0] = *(const f32x4*)p;
      a0[m][kk][1] = *(const f32x4*)(p + 4);
    }

  __syncthreads();   // codebook + ca resident (the kernel's only full barrier)

  // ---- issue half-1 loads, convert half-0 under their latency, then half-1
  f32x4 a1[2][2][2];
  #pragma unroll
  for (int m = 0; m < 2; ++m)
    #pragma unroll
    for (int kk = 0; kk < 2; ++kk) {
      const float* p = zb + ((m + 2) * 16 + c15) * DIM + kk * 32 + g * 8;
      a1[m][kk][0] = *(const f32x4*)p;
      a1[m][kk][1] = *(const f32x4*)(p + 4);
    }

  bf16x8 ah[4][2];
  float zsq = 0.0f;
  #pragma unroll
  for (int m = 0; m < 2; ++m)
    #pragma unroll
    for (int kk = 0; kk < 2; ++kk)
      #pragma unroll
      for (int j = 0; j < 4; ++j) {
        const float v0 = a0[m][kk][0][j], v1 = a0[m][kk][1][j];
        ah[m][kk][j]     = f32_bf16(v0);
        ah[m][kk][j + 4] = f32_bf16(v1);
        zsq += v0 * v0 + v1 * v1;
      }
  #pragma unroll
  for (int m = 0; m < 2; ++m)
    #pragma unroll
    for (int kk = 0; kk < 2; ++kk)
      #pragma unroll
      for (int j = 0; j < 4; ++j) {
        const float v0 = a1[m][kk][0][j], v1 = a1[m][kk][1][j];
        ah[m + 2][kk][j]     = f32_bf16(v0);
        ah[m + 2][kk][j + 4] = f32_bf16(v1);
        zsq += v0 * v0 + v1 * v1;
      }

  // ---- single sweep: 64 rows x 1024 codes, named ping-pong B regs, no barriers
  unsigned best[4][4];
  #pragma unroll
  for (int m = 0; m < 4; ++m)
    #pragma unroll
    for (int r = 0; r < 4; ++r) best[m][r] = 0u;

  const char* bsp = (const char*)Bs;
  const int bx0 = (g ^ sw) << 4;         // kk=0 chunk slot (swizzled)
  const int bx1 = ((4 + g) ^ sw) << 4;   // kk=1 chunk slot

  auto LDB = [&](int t, bf16x8& b00, bf16x8& b01, bf16x8& b10, bf16x8& b11) {
    const int r0 = (t * 32 + c15) * 128;
    b00 = *(const bf16x8*)(bsp + r0 + bx0);
    b01 = *(const bf16x8*)(bsp + r0 + bx1);
    b10 = *(const bf16x8*)(bsp + r0 + 2048 + bx0);
    b11 = *(const bf16x8*)(bsp + r0 + 2048 + bx1);
  };
  auto MM = [&](int t, bf16x8 b00, bf16x8 b01, bf16x8 b10, bf16x8 b11) {
    #pragma unroll
    for (int n = 0; n < 2; ++n) {
      const bf16x8 f0 = n ? b10 : b00;
      const bf16x8 f1 = n ? b11 : b01;
      const float can = ca_s[t * 32 + n * 16 + c15];
      const f32x4 cv = {can, can, can, can};
      const unsigned cc = 1023u - (unsigned)(t * 32 + n * 16 + c15);
      #pragma unroll
      for (int m = 0; m < 4; ++m) {
        f32x4 acc = __builtin_amdgcn_mfma_f32_16x16x32_bf16(
            ah[m][0], f0, cv, 0, 0, 0);
        acc = __builtin_amdgcn_mfma_f32_16x16x32_bf16(
            ah[m][1], f1, acc, 0, 0, 0);
        #pragma unroll
        for (int r = 0; r < 4; ++r) {
          const unsigned key =
              (__builtin_bit_cast(unsigned, acc[r]) & kmask) | cc;  // v_and_or
          best[m][r] = key > best[m][r] ? key : best[m][r];         // v_max_u32
        }
      }
    }
  };

  bf16x8 x00, x01, x10, x11, y00, y01, y10, y11;
  LDB(0, x00, x01, x10, x11);
  #pragma unroll 1
  for (int t2 = 0; t2 < 16; ++t2) {
    LDB(t2 * 2 + 1, y00, y01, y10, y11);
    MM(t2 * 2, x00, x01, x10, x11);
    LDB((t2 * 2 + 2) & 31, x00, x01, x10, x11);  // last wraps to 0 (unused)
    MM(t2 * 2 + 1, y00, y01, y10, y11);
  }

  // ---- epilogue: in-wave winner resolve, gather cb row -> out, loss partial
  float lossx = 0.0f;
  const f32x4* cb4 = (const f32x4*)cb;
  f32x4* out4 = (f32x4*)out;
  #pragma unroll
  for (int m = 0; m < 4; ++m)
    #pragma unroll
    for (int r = 0; r < 4; ++r) {
      unsigned bk = best[m][r];
      #pragma unroll
      for (int w = 1; w < 16; w <<= 1) {
        const unsigned ob = (unsigned)__shfl_xor((int)bk, w, 64);
        bk = ob > bk ? ob : bk;
      }
      const int row = m * 16 + g * 4 + r;          // within wave's 64
      const int bi = 1023 - (int)(bk & 1023u);
      out4[(wrow + row) * 16 + c15] = cb4[bi * 16 + c15];
      if (c15 == 0) lossx += 128.0f - __builtin_bit_cast(float, bk & kmask);
    }

  // ---- per-block loss partial (deterministic; no atomics)
  float psum = zsq + lossx * (1.0f / 512.0f);
  #pragma unroll
  for (int w = 32; w >= 1; w >>= 1) psum += __shfl_xor(psum, w, 64);
  if (lane == 0) sml[wv] = psum;
  __syncthreads();
  if (tid == 0) {
    double t = 0.0;
    #pragma unroll
    for (int i = 0; i < 8; ++i) t += (double)sml[i];
    part[blockIdx.x] = t;
  }
}

// ---------------- kernel 3: finalize loss (deterministic tree) ----------------
__global__ __launch_bounds__(256) void vq_finalize(
    const double* __restrict__ part, float* __restrict__ out_loss) {
  __shared__ double s[4];
  const int tid = threadIdx.x, lane = tid & 63, wv = tid >> 6;
  double v = part[tid];
  #pragma unroll
  for (int w = 32; w >= 1; w >>= 1) v += __shfl_xor(v, w, 64);
  if (lane == 0) s[wv] = v;
  __syncthreads();
  if (tid == 0)
    out_loss[0] = (float)(1.25 * (s[0] + s[1] + s[2] + s[3]) /
                          ((double)N_TOKENS * (double)DIM));
}

extern "C" void kernel_launch(void* const* d_in, const int* in_sizes, int n_in,
                              void* d_out, int out_size, void* d_ws, size_t ws_size,
                              hipStream_t stream) {
  const float* z = (const float*)d_in[0];
  const float* cb = (const float*)d_in[1];
  float* out = (float*)d_out;
  char* ws = (char*)d_ws;

  // workspace layout (137216 bytes used)
  unsigned short* ch = (unsigned short*)(ws);        // 128 KB bf16 codebook*1024
  float* ca2 = (float*)(ws + 131072);                // 4 KB   128 - ||E'||^2/2048
  double* part = (double*)(ws + 135168);             // 2 KB   per-block loss partials

  (void)hipFuncSetAttribute((const void*)vq_argmin,
                            hipFuncAttributeMaxDynamicSharedMemorySize, DYN_LDS);

  vq_prep<<<256, 256, 0, stream>>>(cb, ch, ca2);
  vq_argmin<<<256, 512, DYN_LDS, stream>>>(z, ch, ca2, cb, out, part);
  vq_finalize<<<1, 256, 0, stream>>>(part, out + (size_t)N_TOKENS * DIM);
}

// Round 8
// 33.787 us; speedup vs baseline: 2.1479x; 1.0347x over previous
//
#include <hip/hip_runtime.h>

// VectorQuantizer on MI355X (gfx950) — v8 = v7 + pinned VGPR budget + deeper
// prefetch (ca in ping-pong) + setprio around MFMA.
// out[0 .. 8388607] = codebook[argmin_k ||z - E_k||^2]   (f32)
// out[8388608]      = 1.25 * mean((z_q - z)^2)           (f32)
//
// Score: maximize  s + ca,  s = z.(1024 E_k) via bf16 MFMA, ca = 128 -
// ||1024 E_k||^2/2048 as the MFMA C-operand.  Key = (bits(s+ca) & 0xFFFFFC00)
// | (1023-col); u32 max = argmax + earliest-col tie-break (np.argmin rule).
// Loss fused: ||q-z||^2_row = ||z||^2 + (128 - v*)/512.
//
// v8 key fix: with 132 KB DYNAMIC LDS the compiler cannot see that only
// 2 waves/EU fit, so its occupancy heuristic squeezes VGPRs (v6 measured 80!)
// and serializes everything.  amdgpu_waves_per_eu(2,2) pins the true
// occupancy -> full register budget for the pipelined sweep.

typedef __attribute__((ext_vector_type(8))) short bf16x8;
typedef __attribute__((ext_vector_type(4))) float f32x4;

#define N_TOKENS 131072
#define DIM 64
#define DYN_LDS 135168   // 128 KB bf16 codebook + 4 KB ca

__device__ __forceinline__ short f32_bf16(float f) {
  unsigned u = __builtin_bit_cast(unsigned, f);
  unsigned r = u + 0x7FFFu + ((u >> 16) & 1u);   // round-to-nearest-even
  return (short)(r >> 16);
}

// ---------------- kernel 1: codebook prep -------------------------------------
__global__ __launch_bounds__(256) void vq_prep(
    const float* __restrict__ cb, unsigned short* __restrict__ ch,
    float* __restrict__ ca2) {
  const int lane = threadIdx.x & 63;
  const int wv = threadIdx.x >> 6;
  const int code = blockIdx.x * 4 + wv;      // 256 blocks * 4 waves = 1024 codes
  const float e = cb[code * DIM + lane] * 1024.0f;   // exact pow2 scale
  ch[code * DIM + lane] = (unsigned short)f32_bf16(e);
  float sq = e * e;
  #pragma unroll
  for (int w = 32; w >= 1; w >>= 1) sq += __shfl_xor(sq, w, 64);
  if (lane == 0) ca2[code] = 128.0f - sq * (1.0f / 2048.0f);
}

// ---------------- kernel 2: persistent-codebook argmin + gather + loss --------
__global__ __attribute__((amdgpu_flat_work_group_size(512, 512),
                          amdgpu_waves_per_eu(2, 2)))
void vq_argmin(
    const float* __restrict__ z, const unsigned short* __restrict__ ch,
    const float* __restrict__ ca2, const float* __restrict__ cb,
    float* __restrict__ out, double* __restrict__ part) {
  extern __shared__ char lds[];
  unsigned short* Bs = (unsigned short*)lds;     // [1024 codes][64 dims] bf16, swizzled
  float* ca_s = (float*)(lds + 131072);          // [1024]
  __shared__ float sml[8];

  const int tid = threadIdx.x, lane = tid & 63, wv = tid >> 6;
  const int g = lane >> 4, c15 = lane & 15, sw = c15 & 7;
  const size_t wrow = (size_t)blockIdx.x * 512 + (size_t)wv * 64;
  const unsigned kmask = 0xFFFFFC00u;

  // ---- DMA-stage codebook (+ca) into LDS; source XOR-swizzled, dest linear
  #pragma unroll
  for (int q = 0; q < 16; ++q) {
    const int chunk = q * 512 + tid;           // 16B chunk id, 0..8191
    const int code = chunk >> 3, c = chunk & 7;
    __builtin_amdgcn_global_load_lds(
        (const __attribute__((address_space(1))) unsigned int*)
            (ch + code * DIM + ((c ^ (code & 7)) << 3)),
        (__attribute__((address_space(3))) unsigned int*)(Bs + chunk * 8),
        16, 0, 0);
  }
  if (tid < 256)
    __builtin_amdgcn_global_load_lds(
        (const __attribute__((address_space(1))) unsigned int*)(ca2 + tid * 4),
        (__attribute__((address_space(3))) unsigned int*)(ca_s + tid * 4),
        16, 0, 0);

  // ---- half-0 A loads (rows 0..31 of the wave), in flight across the barrier
  f32x4 a0[2][2][2];
  const float* zb = z + wrow * DIM;
  #pragma unroll
  for (int m = 0; m < 2; ++m)
    #pragma unroll
    for (int kk = 0; kk < 2; ++kk) {
      const float* p = zb + (m * 16 + c15) * DIM + kk * 32 + g * 8;
      a0[m][kk][0] = *(const f32x4*)p;
      a0[m][kk][1] = *(const f32x4*)(p + 4);
    }

  __syncthreads();   // codebook + ca resident (the kernel's only full barrier)

  // ---- issue half-1 loads, convert half-0 under their latency, then half-1
  f32x4 a1[2][2][2];
  #pragma unroll
  for (int m = 0; m < 2; ++m)
    #pragma unroll
    for (int kk = 0; kk < 2; ++kk) {
      const float* p = zb + ((m + 2) * 16 + c15) * DIM + kk * 32 + g * 8;
      a1[m][kk][0] = *(const f32x4*)p;
      a1[m][kk][1] = *(const f32x4*)(p + 4);
    }

  bf16x8 ah[4][2];
  float zsq = 0.0f;
  #pragma unroll
  for (int m = 0; m < 2; ++m)
    #pragma unroll
    for (int kk = 0; kk < 2; ++kk)
      #pragma unroll
      for (int j = 0; j < 4; ++j) {
        const float v0 = a0[m][kk][0][j], v1 = a0[m][kk][1][j];
        ah[m][kk][j]     = f32_bf16(v0);
        ah[m][kk][j + 4] = f32_bf16(v1);
        zsq += v0 * v0 + v1 * v1;
      }
  #pragma unroll
  for (int m = 0; m < 2; ++m)
    #pragma unroll
    for (int kk = 0; kk < 2; ++kk)
      #pragma unroll
      for (int j = 0; j < 4; ++j) {
        const float v0 = a1[m][kk][0][j], v1 = a1[m][kk][1][j];
        ah[m + 2][kk][j]     = f32_bf16(v0);
        ah[m + 2][kk][j + 4] = f32_bf16(v1);
        zsq += v0 * v0 + v1 * v1;
      }

  // ---- single sweep: 64 rows x 1024 codes, ping-pong B+ca regs, no barriers
  unsigned best[4][4];
  #pragma unroll
  for (int m = 0; m < 4; ++m)
    #pragma unroll
    for (int r = 0; r < 4; ++r) best[m][r] = 0u;

  const char* bsp = (const char*)Bs;
  const int bx0 = (g ^ sw) << 4;         // kk=0 chunk slot (swizzled)
  const int bx1 = ((4 + g) ^ sw) << 4;   // kk=1 chunk slot

  auto LDB = [&](int t, bf16x8& b00, bf16x8& b01, bf16x8& b10, bf16x8& b11,
                 float& cA, float& cB) {
    const int r0 = (t * 32 + c15) * 128;
    b00 = *(const bf16x8*)(bsp + r0 + bx0);
    b01 = *(const bf16x8*)(bsp + r0 + bx1);
    b10 = *(const bf16x8*)(bsp + r0 + 2048 + bx0);
    b11 = *(const bf16x8*)(bsp + r0 + 2048 + bx1);
    cA = ca_s[t * 32 + c15];
    cB = ca_s[t * 32 + 16 + c15];
  };
  auto MM = [&](int t, bf16x8 b00, bf16x8 b01, bf16x8 b10, bf16x8 b11,
                float cA, float cB) {
    f32x4 acc[2][4];
    __builtin_amdgcn_s_setprio(1);
    #pragma unroll
    for (int n = 0; n < 2; ++n) {
      const bf16x8 f0 = n ? b10 : b00;
      const bf16x8 f1 = n ? b11 : b01;
      const float can = n ? cB : cA;
      const f32x4 cv = {can, can, can, can};
      #pragma unroll
      for (int m = 0; m < 4; ++m) {
        acc[n][m] = __builtin_amdgcn_mfma_f32_16x16x32_bf16(
            ah[m][0], f0, cv, 0, 0, 0);
        acc[n][m] = __builtin_amdgcn_mfma_f32_16x16x32_bf16(
            ah[m][1], f1, acc[n][m], 0, 0, 0);
      }
    }
    __builtin_amdgcn_s_setprio(0);
    #pragma unroll
    for (int n = 0; n < 2; ++n) {
      const unsigned cc = 1023u - (unsigned)(t * 32 + n * 16 + c15);
      #pragma unroll
      for (int m = 0; m < 4; ++m)
        #pragma unroll
        for (int r = 0; r < 4; ++r) {
          const unsigned key =
              (__builtin_bit_cast(unsigned, acc[n][m][r]) & kmask) | cc;
          best[m][r] = key > best[m][r] ? key : best[m][r];   // v_max_u32
        }
    }
  };

  bf16x8 x00, x01, x10, x11, y00, y01, y10, y11;
  float cx0, cx1, cy0, cy1;
  LDB(0, x00, x01, x10, x11, cx0, cx1);
  #pragma unroll 1
  for (int t2 = 0; t2 < 16; ++t2) {
    LDB(t2 * 2 + 1, y00, y01, y10, y11, cy0, cy1);
    MM(t2 * 2, x00, x01, x10, x11, cx0, cx1);
    LDB((t2 * 2 + 2) & 31, x00, x01, x10, x11, cx0, cx1);  // last wraps (unused)
    MM(t2 * 2 + 1, y00, y01, y10, y11, cy0, cy1);
  }

  // ---- epilogue: in-wave winner resolve, gather cb row -> out, loss partial
  float lossx = 0.0f;
  const f32x4* cb4 = (const f32x4*)cb;
  f32x4* out4 = (f32x4*)out;
  #pragma unroll
  for (int m = 0; m < 4; ++m)
    #pragma unroll
    for (int r = 0; r < 4; ++r) {
      unsigned bk = best[m][r];
      #pragma unroll
      for (int w = 1; w < 16; w <<= 1) {
        const unsigned ob = (unsigned)__shfl_xor((int)bk, w, 64);
        bk = ob > bk ? ob : bk;
      }
      const int row = m * 16 + g * 4 + r;          // within wave's 64
      const int bi = 1023 - (int)(bk & 1023u);
      out4[(wrow + row) * 16 + c15] = cb4[bi * 16 + c15];
      if (c15 == 0) lossx += 128.0f - __builtin_bit_cast(float, bk & kmask);
    }

  // ---- per-block loss partial (deterministic; no atomics)
  float psum = zsq + lossx * (1.0f / 512.0f);
  #pragma unroll
  for (int w = 32; w >= 1; w >>= 1) psum += __shfl_xor(psum, w, 64);
  if (lane == 0) sml[wv] = psum;
  __syncthreads();
  if (tid == 0) {
    double t = 0.0;
    #pragma unroll
    for (int i = 0; i < 8; ++i) t += (double)sml[i];
    part[blockIdx.x] = t;
  }
}

// ---------------- kernel 3: finalize loss (deterministic tree) ----------------
__global__ __launch_bounds__(256) void vq_finalize(
    const double* __restrict__ part, float* __restrict__ out_loss) {
  __shared__ double s[4];
  const int tid = threadIdx.x, lane = tid & 63, wv = tid >> 6;
  double v = part[tid];
  #pragma unroll
  for (int w = 32; w >= 1; w >>= 1) v += __shfl_xor(v, w, 64);
  if (lane == 0) s[wv] = v;
  __syncthreads();
  if (tid == 0)
    out_loss[0] = (float)(1.25 * (s[0] + s[1] + s[2] + s[3]) /
                          ((double)N_TOKENS * (double)DIM));
}

extern "C" void kernel_launch(void* const* d_in, const int* in_sizes, int n_in,
                              void* d_out, int out_size, void* d_ws, size_t ws_size,
                              hipStream_t stream) {
  const float* z = (const float*)d_in[0];
  const float* cb = (const float*)d_in[1];
  float* out = (float*)d_out;
  char* ws = (char*)d_ws;

  // workspace layout (137216 bytes used)
  unsigned short* ch = (unsigned short*)(ws);        // 128 KB bf16 codebook*1024
  float* ca2 = (float*)(ws + 131072);                // 4 KB   128 - ||E'||^2/2048
  double* part = (double*)(ws + 135168);             // 2 KB   per-block loss partials

  (void)hipFuncSetAttribute((const void*)vq_argmin,
                            hipFuncAttributeMaxDynamicSharedMemorySize, DYN_LDS);

  vq_prep<<<256, 256, 0, stream>>>(cb, ch, ca2);
  vq_argmin<<<256, 512, DYN_LDS, stream>>>(z, ch, ca2, cb, out, part);
  vq_finalize<<<1, 256, 0, stream>>>(part, out + (size_t)N_TOKENS * DIM);
}